// Round 11
// baseline (8311.819 us; speedup 1.0000x reference)
//
#include <hip/hip_runtime.h>
#include <hip/hip_bf16.h>

typedef __bf16 bf16;
typedef __attribute__((ext_vector_type(8))) __bf16 bf16x8;
typedef __attribute__((ext_vector_type(4))) __bf16 bf16x4;
typedef __attribute__((ext_vector_type(4))) float f32x4;
typedef __attribute__((ext_vector_type(16))) float f32x16;
typedef __attribute__((ext_vector_type(4))) unsigned int u32x4;
typedef __attribute__((ext_vector_type(2))) unsigned int u32x2;

__device__ __forceinline__ void gload_lds16(const void* g, void* l) {
  __builtin_amdgcn_global_load_lds((const __attribute__((address_space(1))) void*)g,
                                   (__attribute__((address_space(3))) void*)l, 16, 0, 0);
}

// asm variants (hazard-suspect; kept ONLY for shadow control S2)
__device__ __forceinline__ float exp2_fast(float x) {
  float r;
  asm("v_exp_f32 %0, %1" : "=v"(r) : "v"(x));
  return r;
}
__device__ __forceinline__ void plswap(unsigned& a, unsigned& b) {
  asm("v_permlane32_swap_b32 %0, %1" : "+v"(a), "+v"(b));
}

// builtin variants (compiler-managed hazards)
__device__ __forceinline__ float exp2_b(float x) { return __builtin_amdgcn_exp2f(x); }
__device__ __forceinline__ void plswap_b(unsigned& a, unsigned& b) {
  u32x2 r = __builtin_amdgcn_permlane32_swap(a, b, false, false);
  a = r[0]; b = r[1];
}

// cvt_pk: no builtin exists (guide T12/m240); asm form HW-validated, non-TRANS
__device__ __forceinline__ unsigned cvtpk(float lo, float hi) {
  unsigned r;
  asm("v_cvt_pk_bf16_f32 %0, %1, %2" : "=v"(r) : "v"(lo), "v"(hi));
  return r;
}

// ---------------- merged f32->bf16 convert (x,y) + weight transpose-convert ----------------
__global__ __launch_bounds__(256) void cvtw_kernel(
    const float* __restrict__ x, const float* __restrict__ y,
    bf16* __restrict__ xb, bf16* __restrict__ yb,
    const float* __restrict__ W0, const float* __restrict__ W1,
    const float* __restrict__ W2, const float* __restrict__ W3,
    bf16* __restrict__ T0, bf16* __restrict__ T1,
    bf16* __restrict__ T2, bf16* __restrict__ T3) {
  __shared__ float t[32][33];
  const int bid = blockIdx.x, tid = threadIdx.x;
  if (bid < 4096) {
    const int z = bid >> 10, rem = bid & 1023;
    const int bx = rem & 31, by = rem >> 5;
    const float* W; bf16* T;
    switch (z) {
      case 0: W = W0; T = T0; break;
      case 1: W = W1; T = T1; break;
      case 2: W = W2; T = T2; break;
      default: W = W3; T = T3; break;
    }
    const int tx = tid & 31, ty = tid >> 5;
    const int bn = bx * 32, bk = by * 32;
#pragma unroll
    for (int i = 0; i < 32; i += 8)
      t[ty + i][tx] = W[(size_t)(bk + ty + i) * 1024 + bn + tx];
    __syncthreads();
#pragma unroll
    for (int i = 0; i < 32; i += 8)
      T[(size_t)(bn + ty + i) * 1024 + bk + tx] = (bf16)t[tx][ty + i];
  } else {
    const int n4 = 1048576;
    int i = (bid - 4096) * 256 + tid;
    const float4* in = (const float4*)x; bf16x4* out = (bf16x4*)xb;
    if (i >= n4) { in = (const float4*)y; out = (bf16x4*)yb; i -= n4; }
    float4 v = in[i];
    bf16x4 o;
    o[0] = (bf16)v.x; o[1] = (bf16)v.y; o[2] = (bf16)v.z; o[3] = (bf16)v.w;
    out[i] = o;
  }
}

// ---------------- merged Q/K/V projection GEMM, 128x128 tile, 8 waves, double-buffered --------
__global__ __launch_bounds__(512, 6) void gemm_qkv(
    const bf16* __restrict__ xb, const bf16* __restrict__ yb,
    const bf16* __restrict__ Wqt, const bf16* __restrict__ Wkt, const bf16* __restrict__ Wvt,
    const float* __restrict__ bq, const float* __restrict__ bk, const float* __restrict__ bv,
    bf16* __restrict__ Qb, bf16* __restrict__ Kb, bf16* __restrict__ Vtb) {
  constexpr int K = 1024;
  constexpr float QSCALE = (float)(1.4426950408889634 / 45.254833995939045);
  __shared__ bf16 As[2][128 * 32];
  __shared__ bf16 Bs[2][128 * 32];
  const int z = blockIdx.z;
  const bf16* A  = (z == 0) ? xb : yb;
  const bf16* Bt = (z == 0) ? Wqt : (z == 1) ? Wkt : Wvt;
  const float* bias = (z == 0) ? bq : (z == 1) ? bk : bv;

  const int tid = threadIdx.x;
  const int wave = tid >> 6, lane = tid & 63;
  const int g = lane >> 4, r15 = lane & 15;
  const int m0 = blockIdx.x * 128, n0 = blockIdx.y * 128;
  const int wr = wave >> 2, wc = wave & 3;

  f32x4 acc[4][2] = {};

  const int rowA = tid >> 2, chA = tid & 3;

  auto stage = [&](int buf, int k0) {
    gload_lds16(A  + (size_t)(m0 + rowA) * K + k0 + chA * 8, (char*)As[buf] + tid * 16);
    gload_lds16(Bt + (size_t)(n0 + rowA) * K + k0 + chA * 8, (char*)Bs[buf] + tid * 16);
  };

  stage(0, 0);
  __syncthreads();
  int cur = 0;
  for (int t = 0; t < K / 32; ++t) {
    if (t + 1 < K / 32) stage(cur ^ 1, (t + 1) * 32);
    bf16x8 af[4], bfr[2];
#pragma unroll
    for (int mi = 0; mi < 4; ++mi)
      af[mi] = *(const bf16x8*)((const char*)As[cur] + ((wr * 64 + mi * 16 + r15) * 64 + g * 16));
#pragma unroll
    for (int nj = 0; nj < 2; ++nj)
      bfr[nj] = *(const bf16x8*)((const char*)Bs[cur] + ((wc * 32 + nj * 16 + r15) * 64 + g * 16));
#pragma unroll
    for (int mi = 0; mi < 4; ++mi)
#pragma unroll
      for (int nj = 0; nj < 2; ++nj)
        acc[mi][nj] = __builtin_amdgcn_mfma_f32_16x16x32_bf16(af[mi], bfr[nj], acc[mi][nj], 0, 0, 0);
    __syncthreads();
    cur ^= 1;
  }

  const float scl = (z == 0) ? QSCALE : 1.0f;
#pragma unroll
  for (int mi = 0; mi < 4; ++mi) {
#pragma unroll
    for (int nj = 0; nj < 2; ++nj) {
      int row = m0 + wr * 64 + mi * 16 + g * 4;
      int col = n0 + wc * 32 + nj * 16 + r15;
      float bv_ = bias[col];
      if (z < 2) {
        bf16* C = (z == 0) ? Qb : Kb;
#pragma unroll
        for (int r = 0; r < 4; ++r)
          C[(size_t)(row + r) * 1024 + col] = (bf16)((acc[mi][nj][r] + bv_) * scl);
      } else {
        int b = row >> 11, n = row & 2047;
        bf16x4 pkv;
#pragma unroll
        for (int r = 0; r < 4; ++r)
          pkv[r] = (bf16)(acc[mi][nj][r] + bv_);
        *(bf16x4*)(Vtb + ((size_t)b * 1024 + col) * 2048 + n) = pkv;
      }
    }
  }
}

// ---------------- out-projection GEMM, 128x64 tile, 8 waves, bias+ReLU, f32 out ----------------
__global__ __launch_bounds__(512, 4) void gemm_out(
    const bf16* __restrict__ A, const bf16* __restrict__ Bt,
    const float* __restrict__ bias, float* __restrict__ C) {
  constexpr int K = 1024;
  __shared__ bf16 As[2][128 * 32];
  __shared__ bf16 Bs[2][64 * 32];
  const int tid = threadIdx.x;
  const int wave = tid >> 6, lane = tid & 63;
  const int g = lane >> 4, r15 = lane & 15;
  const int m0 = blockIdx.x * 128, n0 = blockIdx.y * 64;
  const int wr = wave >> 1, wc = wave & 1;

  f32x4 acc[2][2] = {};

  const int rowA = tid >> 2, chA = tid & 3;

  auto stage = [&](int buf, int k0) {
    gload_lds16(A + (size_t)(m0 + rowA) * K + k0 + chA * 8, (char*)As[buf] + tid * 16);
    if (tid < 256)
      gload_lds16(Bt + (size_t)(n0 + rowA) * K + k0 + chA * 8, (char*)Bs[buf] + tid * 16);
  };

  stage(0, 0);
  __syncthreads();
  int cur = 0;
  for (int t = 0; t < K / 32; ++t) {
    if (t + 1 < K / 32) stage(cur ^ 1, (t + 1) * 32);
    bf16x8 af[2], bfr[2];
#pragma unroll
    for (int mi = 0; mi < 2; ++mi)
      af[mi] = *(const bf16x8*)((const char*)As[cur] + ((wr * 32 + mi * 16 + r15) * 64 + g * 16));
#pragma unroll
    for (int nj = 0; nj < 2; ++nj)
      bfr[nj] = *(const bf16x8*)((const char*)Bs[cur] + ((wc * 32 + nj * 16 + r15) * 64 + g * 16));
#pragma unroll
    for (int mi = 0; mi < 2; ++mi)
#pragma unroll
      for (int nj = 0; nj < 2; ++nj)
        acc[mi][nj] = __builtin_amdgcn_mfma_f32_16x16x32_bf16(af[mi], bfr[nj], acc[mi][nj], 0, 0, 0);
    __syncthreads();
    cur ^= 1;
  }

#pragma unroll
  for (int mi = 0; mi < 2; ++mi)
#pragma unroll
    for (int nj = 0; nj < 2; ++nj) {
      int row = m0 + wr * 32 + mi * 16 + g * 4;
      int col = n0 + wc * 32 + nj * 16 + r15;
      float bv_ = bias[col];
#pragma unroll
      for (int r = 0; r < 4; ++r)
        C[(size_t)(row + r) * 1024 + col] = fmaxf(acc[mi][nj][r] + bv_, 0.0f);
    }
}

// ---------------- flash attention v5-builtin (real output path): asm exp/permlane -> builtins --
__global__ __launch_bounds__(128, 2) void attn_kernel(
    const bf16* __restrict__ Q, const bf16* __restrict__ Kin,
    const bf16* __restrict__ Vt, bf16* __restrict__ Oa) {
  __shared__ bf16 Ks[2][64 * 64];
  __shared__ bf16 Vs[2][64 * 64];
  __shared__ float lsh[2][2][32];
  const int tid = threadIdx.x;
  const int w = tid >> 6, lane = tid & 63;
  const int q5 = lane & 31, h = lane >> 5;

  int i = blockIdx.y * 32 + blockIdx.x;
  int xcd = i & 7, slot = i >> 3;
  int bh = xcd * 4 + (slot >> 5), qt = slot & 31;
  int b = bh >> 4, hd = bh & 15;

  const bf16* Qg = Q + ((size_t)b * 2048 + qt * 64) * 1024 + hd * 64;
  const bf16* Kg = Kin + (size_t)b * 2048 * 1024 + hd * 64;
  const bf16* Vg = Vt + ((size_t)b * 1024 + hd * 64) * 2048;

  bf16x8 qf[2][4];
#pragma unroll
  for (int qb = 0; qb < 2; ++qb)
#pragma unroll
    for (int ks = 0; ks < 4; ++ks)
      qf[qb][ks] = *(const bf16x8*)(Qg + (size_t)(qb * 32 + q5) * 1024 + ks * 16 + h * 8);

  f32x16 o[2][2] = {};
  float ls[2] = {};

  auto stage = [&](int buf, int kv0) {
#pragma unroll
    for (int ii = 0; ii < 4; ++ii) {
      int c = tid + ii * 128;
      int row = c >> 3;
      int sl = (c & 7) ^ (row & 7) ^ ((row >> 3) & 1);
      gload_lds16(Kg + (size_t)(kv0 + row) * 1024 + sl * 8, (char*)Ks[buf] + c * 16);
      gload_lds16(Vg + (size_t)row * 2048 + kv0 + sl * 8, (char*)Vs[buf] + c * 16);
    }
  };

  stage(0, 0);
  __syncthreads();
  int cur = 0;

  const int krow = w * 32 + q5;
  const int kswz = (krow & 7) ^ ((krow >> 3) & 1);

  unsigned uA[2][8], uB[2][8];
  bf16x8 vA[4], vB[4];

  auto phase = [&](int t, unsigned (&uin)[2][8], unsigned (&uout)[2][8],
                   bf16x8 (&vin)[4], bf16x8 (&vout)[4], bool doStage, bool doPV) {
    if (doStage) stage(cur ^ 1, (t + 1) * 64);

    f32x16 s[2] = {};
    __builtin_amdgcn_s_setprio(1);
#pragma unroll
    for (int ks = 0; ks < 4; ++ks) {
      bf16x8 kf = *(const bf16x8*)((const char*)Ks[cur] + krow * 128 + (((2 * ks + h) ^ kswz) << 4));
      s[0] = __builtin_amdgcn_mfma_f32_32x32x16_bf16(kf, qf[0][ks], s[0], 0, 0, 0);
      s[1] = __builtin_amdgcn_mfma_f32_32x32x16_bf16(kf, qf[1][ks], s[1], 0, 0, 0);
    }

#pragma unroll
    for (int j = 0; j < 2; ++j) {
      const int db = w ^ j;
      const int vrow0 = db * 32 + q5;
      const int vswz = (vrow0 & 7) ^ ((vrow0 >> 3) & 1);
#pragma unroll
      for (int kap = 0; kap < 2; ++kap)
        vout[2 * j + kap] = *(const bf16x8*)((const char*)Vs[cur] + vrow0 * 128 +
                                             (((4 * w + 2 * kap + h) ^ vswz) << 4));
    }

    if (doPV) {
#pragma unroll
      for (int j = 0; j < 2; ++j)
#pragma unroll
        for (int kap = 0; kap < 2; ++kap)
#pragma unroll
          for (int qb = 0; qb < 2; ++qb) {
            u32x4 uw;
            uw[0] = uin[qb][4 * kap + 0]; uw[1] = uin[qb][4 * kap + 1];
            uw[2] = uin[qb][4 * kap + 2]; uw[3] = uin[qb][4 * kap + 3];
            bf16x8 pa = __builtin_bit_cast(bf16x8, uw);
            o[qb][j] = __builtin_amdgcn_mfma_f32_32x32x16_bf16(pa, vin[2 * j + kap], o[qb][j], 0, 0, 0);
          }
    }
    __builtin_amdgcn_s_setprio(0);

#pragma unroll
    for (int qb = 0; qb < 2; ++qb) {
      float e[16];
#pragma unroll
      for (int jj = 0; jj < 16; ++jj) e[jj] = exp2_b(s[qb][jj]);
      ls[qb] += ((((e[0] + e[1]) + (e[2] + e[3])) + ((e[4] + e[5]) + (e[6] + e[7]))) +
                 (((e[8] + e[9]) + (e[10] + e[11])) + ((e[12] + e[13]) + (e[14] + e[15]))));
#pragma unroll
      for (int p = 0; p < 8; ++p) uout[qb][p] = cvtpk(e[2 * p], e[2 * p + 1]);
      plswap_b(uout[qb][0], uout[qb][2]); plswap_b(uout[qb][1], uout[qb][3]);
      plswap_b(uout[qb][4], uout[qb][6]); plswap_b(uout[qb][5], uout[qb][7]);
    }

    __syncthreads();
    cur ^= 1;
  };

  phase(0, uB, uA, vB, vA, true, false);
  for (int t = 1; t < 31; t += 2) {
    phase(t, uA, uB, vA, vB, true, true);
    phase(t + 1, uB, uA, vB, vA, true, true);
  }
  phase(31, uA, uB, vA, vB, false, true);
#pragma unroll
  for (int j = 0; j < 2; ++j)
#pragma unroll
    for (int kap = 0; kap < 2; ++kap)
#pragma unroll
      for (int qb = 0; qb < 2; ++qb) {
        u32x4 uw;
        uw[0] = uB[qb][4 * kap + 0]; uw[1] = uB[qb][4 * kap + 1];
        uw[2] = uB[qb][4 * kap + 2]; uw[3] = uB[qb][4 * kap + 3];
        bf16x8 pa = __builtin_bit_cast(bf16x8, uw);
        o[qb][j] = __builtin_amdgcn_mfma_f32_32x32x16_bf16(pa, vB[2 * j + kap], o[qb][j], 0, 0, 0);
      }

  ls[0] += __shfl_xor(ls[0], 32);
  ls[1] += __shfl_xor(ls[1], 32);
  if (h == 0) { lsh[w][0][q5] = ls[0]; lsh[w][1][q5] = ls[1]; }

  float* osh = (float*)Ks;
#pragma unroll
  for (int qb = 0; qb < 2; ++qb)
    *(f32x16*)(osh + ((w * 2 + qb) * 64 + lane) * 16) = o[qb][1];
  __syncthreads();

#pragma unroll
  for (int qb = 0; qb < 2; ++qb) {
    float lt = ls[qb] + lsh[1 - w][qb][q5];
    float iv = __builtin_amdgcn_rcpf(lt);
    f32x16 p = *(const f32x16*)(osh + (((1 - w) * 2 + qb) * 64 + lane) * 16);
#pragma unroll
    for (int g4 = 0; g4 < 4; ++g4)
#pragma unroll
      for (int r = 0; r < 4; ++r) {
        int qr = g4 * 8 + 4 * h + r;
        float il = __shfl(iv, qr);
        size_t row = (size_t)b * 2048 + qt * 64 + qb * 32 + qr;
        Oa[row * 1024 + hd * 64 + w * 32 + q5] = (bf16)((o[qb][0][g4 * 4 + r] + p[g4 * 4 + r]) * il);
      }
  }
}

// ---------------- shared v8 body: BUILTIN=1 uses hazard-safe builtins, 0 uses raw asm ----------
template <int BUILTIN>
__device__ __forceinline__ void attn_v8_body(
    const bf16* __restrict__ Q, const bf16* __restrict__ Kin,
    const bf16* __restrict__ Vt, bf16* __restrict__ Oa,
    bf16 (*Ks)[64 * 64], float (*lsh)[32]) {
  const int tid = threadIdx.x;
  const int w = tid >> 6, lane = tid & 63;
  const int q5 = lane & 31, h = lane >> 5;

  int i = blockIdx.y * 64 + blockIdx.x;
  int xcd = i & 7, slot = i >> 3;
  int bh = xcd * 4 + (slot >> 6), qt = slot & 63;
  int b = bh >> 4, hd = bh & 15;

  const bf16* Qg = Q + ((size_t)b * 2048 + qt * 32) * 1024 + hd * 64;
  const bf16* Kg = Kin + (size_t)b * 2048 * 1024 + hd * 64;
  const bf16* Vg = Vt + ((size_t)b * 1024 + hd * 64) * 2048;

  bf16x8 qf[4];
#pragma unroll
  for (int ks = 0; ks < 4; ++ks)
    qf[ks] = *(const bf16x8*)(Qg + (size_t)q5 * 1024 + ks * 16 + h * 8);

  f32x16 o[2] = {};
  float ls = 0.0f;

  auto stage = [&](int buf, int kv0) {
#pragma unroll
    for (int ii = 0; ii < 4; ++ii) {
      int c = tid + ii * 128;
      int row = c >> 3;
      int sl = (c & 7) ^ (row & 7) ^ ((row >> 3) & 1);
      gload_lds16(Kg + (size_t)(kv0 + row) * 1024 + sl * 8, (char*)Ks[buf] + c * 16);
    }
  };

  stage(0, 0);
  __syncthreads();
  int cur = 0;

  const int krow = w * 32 + q5;
  const int kswz = (krow & 7) ^ ((krow >> 3) & 1);

  unsigned uA[8], uB[8];
  bf16x8 vA[4], vB[4];

  auto phase = [&](int t, unsigned (&uin)[8], unsigned (&uout)[8],
                   bf16x8 (&vin)[4], bf16x8 (&vout)[4], bool doStage, bool doPV) {
    if (doStage) stage(cur ^ 1, (t + 1) * 64);

    f32x16 s = {};
    __builtin_amdgcn_s_setprio(1);
#pragma unroll
    for (int ks = 0; ks < 4; ++ks) {
      bf16x8 kf = *(const bf16x8*)((const char*)Ks[cur] + krow * 128 + (((2 * ks + h) ^ kswz) << 4));
      s = __builtin_amdgcn_mfma_f32_32x32x16_bf16(kf, qf[ks], s, 0, 0, 0);
    }

#pragma unroll
    for (int j = 0; j < 2; ++j) {
      const int db = w ^ j;
#pragma unroll
      for (int kap = 0; kap < 2; ++kap)
        vout[2 * j + kap] = *(const bf16x8*)(Vg + (size_t)(db * 32 + q5) * 2048 +
                                            t * 64 + (4 * w + 2 * kap + h) * 8);
    }

    if (doPV) {
#pragma unroll
      for (int j = 0; j < 2; ++j)
#pragma unroll
        for (int kap = 0; kap < 2; ++kap) {
          u32x4 uw;
          uw[0] = uin[4 * kap + 0]; uw[1] = uin[4 * kap + 1];
          uw[2] = uin[4 * kap + 2]; uw[3] = uin[4 * kap + 3];
          bf16x8 pa = __builtin_bit_cast(bf16x8, uw);
          o[j] = __builtin_amdgcn_mfma_f32_32x32x16_bf16(pa, vin[2 * j + kap], o[j], 0, 0, 0);
        }
    }
    __builtin_amdgcn_s_setprio(0);

    float e[16];
#pragma unroll
    for (int jj = 0; jj < 16; ++jj)
      e[jj] = BUILTIN ? exp2_b(s[jj]) : exp2_fast(s[jj]);
    ls += ((((e[0] + e[1]) + (e[2] + e[3])) + ((e[4] + e[5]) + (e[6] + e[7]))) +
           (((e[8] + e[9]) + (e[10] + e[11])) + ((e[12] + e[13]) + (e[14] + e[15]))));
#pragma unroll
    for (int p = 0; p < 8; ++p) uout[p] = cvtpk(e[2 * p], e[2 * p + 1]);
    if (BUILTIN) {
      plswap_b(uout[0], uout[2]); plswap_b(uout[1], uout[3]);
      plswap_b(uout[4], uout[6]); plswap_b(uout[5], uout[7]);
    } else {
      plswap(uout[0], uout[2]); plswap(uout[1], uout[3]);
      plswap(uout[4], uout[6]); plswap(uout[5], uout[7]);
    }

    __syncthreads();
    cur ^= 1;
  };

  phase(0, uB, uA, vB, vA, true, false);
  for (int t = 1; t < 31; t += 2) {
    phase(t, uA, uB, vA, vB, true, true);
    phase(t + 1, uB, uA, vB, vA, true, true);
  }
  phase(31, uA, uB, vA, vB, false, true);
#pragma unroll
  for (int j = 0; j < 2; ++j)
#pragma unroll
    for (int kap = 0; kap < 2; ++kap) {
      u32x4 uw;
      uw[0] = uB[4 * kap + 0]; uw[1] = uB[4 * kap + 1];
      uw[2] = uB[4 * kap + 2]; uw[3] = uB[4 * kap + 3];
      bf16x8 pa = __builtin_bit_cast(bf16x8, uw);
      o[j] = __builtin_amdgcn_mfma_f32_32x32x16_bf16(pa, vB[2 * j + kap], o[j], 0, 0, 0);
    }

  ls += __shfl_xor(ls, 32);
  if (h == 0) lsh[w][q5] = ls;

  float* osh = (float*)Ks;
  *(f32x16*)(osh + ((size_t)(w * 64 + lane)) * 16) = o[1];
  __syncthreads();

  const int pw = 1 - w;
  float lt = ls + lsh[pw][q5];
  float iv = __builtin_amdgcn_rcpf(lt);
  f32x16 p = *(const f32x16*)(osh + ((size_t)(pw * 64 + lane)) * 16);
#pragma unroll
  for (int g4 = 0; g4 < 4; ++g4)
#pragma unroll
    for (int r = 0; r < 4; ++r) {
      int qr = g4 * 8 + 4 * h + r;
      float il = __shfl(iv, qr);
      size_t row = (size_t)b * 2048 + qt * 32 + qr;
      Oa[row * 1024 + hd * 64 + w * 32 + q5] = (bf16)((o[0][g4 * 4 + r] + p[g4 * 4 + r]) * il);
    }
}

// SHADOW 1: v8 with builtins (hazard-fix candidate)
__global__ __launch_bounds__(128, 4) void attn_v8b(
    const bf16* __restrict__ Q, const bf16* __restrict__ Kin,
    const bf16* __restrict__ Vt, bf16* __restrict__ Oa) {
  __shared__ bf16 Ks[2][64 * 64];
  __shared__ float lsh[2][32];
  attn_v8_body<1>(Q, Kin, Vt, Oa, Ks, lsh);
}

// SHADOW 2: v8 with raw asm (known-bad control, R9)
__global__ __launch_bounds__(128, 4) void attn_v8a(
    const bf16* __restrict__ Q, const bf16* __restrict__ Kin,
    const bf16* __restrict__ Vt, bf16* __restrict__ Oa) {
  __shared__ bf16 Ks[2][64 * 64];
  __shared__ float lsh[2][32];
  attn_v8_body<0>(Q, Kin, Vt, Oa, Ks, lsh);
}

// ---------------- diagnostics ----------------
__global__ void zeroflags_kernel(unsigned* flags) {
  if (threadIdx.x < 2) flags[threadIdx.x] = 0;
}

__global__ __launch_bounds__(256) void check_kernel(const bf16* __restrict__ a,
                                                    const bf16* __restrict__ b,
                                                    const bf16* __restrict__ c,
                                                    unsigned* __restrict__ flags) {
  size_t i0 = ((size_t)blockIdx.x * 256 + threadIdx.x) * 8;
  int c1 = 0, c2 = 0;
#pragma unroll
  for (int k = 0; k < 8; ++k) {
    float ra = (float)a[i0 + k];
    if (fabsf(ra - (float)b[i0 + k]) > 2e-3f) c1++;
    if (fabsf(ra - (float)c[i0 + k]) > 2e-3f) c2++;
  }
  if (c1) atomicAdd(&flags[0], (unsigned)c1);
  if (c2) atomicAdd(&flags[1], (unsigned)c2);
}

// split burns: each fires ONLY on its own flag -> unambiguous decode by kernel name in rocprof
__global__ void burn1_kernel(const unsigned* __restrict__ flags, float* __restrict__ sink) {
  if (blockIdx.x == 0 && threadIdx.x == 0 && flags[0]) {
    float v = 1.0f;
#pragma unroll 1
    for (int i = 0; i < 600000; ++i) v = __builtin_fmaf(v, 1.0000001f, 1e-7f);
    sink[0] = v;
  }
}
__global__ void burn2_kernel(const unsigned* __restrict__ flags, float* __restrict__ sink) {
  if (blockIdx.x == 0 && threadIdx.x == 0 && flags[1]) {
    float v = 1.0f;
#pragma unroll 1
    for (int i = 0; i < 600000; ++i) v = __builtin_fmaf(v, 1.0000001f, 1e-7f);
    sink[1] = v;
  }
}

extern "C" void kernel_launch(void* const* d_in, const int* in_sizes, int n_in,
                              void* d_out, int out_size, void* d_ws, size_t ws_size,
                              hipStream_t stream) {
  (void)in_sizes; (void)n_in; (void)out_size;
  const float* x  = (const float*)d_in[0];
  const float* y  = (const float*)d_in[1];
  const float* Wq = (const float*)d_in[2];
  const float* bq = (const float*)d_in[3];
  const float* Wk = (const float*)d_in[4];
  const float* bk = (const float*)d_in[5];
  const float* Wv = (const float*)d_in[6];
  const float* bv = (const float*)d_in[7];
  const float* Wo = (const float*)d_in[8];
  const float* bo = (const float*)d_in[9];

  char* ws = (char*)d_ws;
  bf16* xb  = (bf16*)(ws + 0);
  bf16* yb  = (bf16*)(ws + 8388608);
  bf16* Qb  = (bf16*)(ws + 16777216);
  bf16* Kb  = (bf16*)(ws + 25165824);
  bf16* Vtb = (bf16*)(ws + 33554432);
  bf16* Oab = (bf16*)(ws + 41943040);
  bf16* Wqt = (bf16*)(ws + 50331648);
  bf16* Wkt = (bf16*)(ws + 52428800);
  bf16* Wvt = (bf16*)(ws + 54525952);
  bf16* Wot = (bf16*)(ws + 56623104);
  bf16* Oab2 = (bf16*)(ws + 58720256);
  bf16* Oab3 = (bf16*)(ws + 67108864);
  unsigned* flags = (unsigned*)(ws + 75497472);
  float* sink = (float*)(ws + 75497488);
  const bool diag = (ws_size >= 75497600);

  cvtw_kernel<<<12288, 256, 0, stream>>>(x, y, xb, yb, Wq, Wk, Wv, Wo, Wqt, Wkt, Wvt, Wot);
  gemm_qkv<<<dim3(32, 8, 3), 512, 0, stream>>>(xb, yb, Wqt, Wkt, Wvt, bq, bk, bv, Qb, Kb, Vtb);
  if (diag) {
    attn_v8b<<<dim3(64, 32), dim3(128), 0, stream>>>(Qb, Kb, Vtb, Oab2);
    attn_v8a<<<dim3(64, 32), dim3(128), 0, stream>>>(Qb, Kb, Vtb, Oab3);
  }
  attn_kernel<<<dim3(32, 32), dim3(128), 0, stream>>>(Qb, Kb, Vtb, Oab);
  if (diag) {
    zeroflags_kernel<<<1, 64, 0, stream>>>(flags);
    check_kernel<<<2048, 256, 0, stream>>>(Oab, Oab2, Oab3, flags);
    burn1_kernel<<<1, 64, 0, stream>>>(flags, sink);
    burn2_kernel<<<1, 64, 0, stream>>>(flags, sink);
  }
  gemm_out<<<dim3(32, 16), 512, 0, stream>>>(Oab, Wot, bo, (float*)d_out);
}

// Round 12
// 148.543 us; speedup vs baseline: 55.9555x; 55.9555x over previous
//
#include <hip/hip_runtime.h>
#include <hip/hip_bf16.h>

typedef __bf16 bf16;
typedef __attribute__((ext_vector_type(8))) __bf16 bf16x8;
typedef __attribute__((ext_vector_type(4))) __bf16 bf16x4;
typedef __attribute__((ext_vector_type(4))) float f32x4;
typedef __attribute__((ext_vector_type(16))) float f32x16;
typedef __attribute__((ext_vector_type(4))) unsigned int u32x4;
typedef __attribute__((ext_vector_type(2))) unsigned int u32x2;

__device__ __forceinline__ void gload_lds16(const void* g, void* l) {
  __builtin_amdgcn_global_load_lds((const __attribute__((address_space(1))) void*)g,
                                   (__attribute__((address_space(3))) void*)l, 16, 0, 0);
}

// NOTE (R11 lesson): raw inline-asm v_exp_f32 / v_permlane32_swap lack compiler-managed
// result-use hazard handling -> schedule-dependent corruption (R6/R7/R9). Builtins only.
__device__ __forceinline__ float exp2_b(float x) { return __builtin_amdgcn_exp2f(x); }
__device__ __forceinline__ void plswap_b(unsigned& a, unsigned& b) {
  u32x2 r = __builtin_amdgcn_permlane32_swap(a, b, false, false);
  a = r[0]; b = r[1];
}
// cvt_pk: no builtin exists; non-TRANS VALU op, oracle-validated safe in asm.
__device__ __forceinline__ unsigned cvtpk(float lo, float hi) {
  unsigned r;
  asm("v_cvt_pk_bf16_f32 %0, %1, %2" : "=v"(r) : "v"(lo), "v"(hi));
  return r;
}

// ---------------- merged f32->bf16 convert (x,y) + weight transpose-convert ----------------
__global__ __launch_bounds__(256) void cvtw_kernel(
    const float* __restrict__ x, const float* __restrict__ y,
    bf16* __restrict__ xb, bf16* __restrict__ yb,
    const float* __restrict__ W0, const float* __restrict__ W1,
    const float* __restrict__ W2, const float* __restrict__ W3,
    bf16* __restrict__ T0, bf16* __restrict__ T1,
    bf16* __restrict__ T2, bf16* __restrict__ T3) {
  __shared__ float t[32][33];
  const int bid = blockIdx.x, tid = threadIdx.x;
  if (bid < 4096) {
    const int z = bid >> 10, rem = bid & 1023;
    const int bx = rem & 31, by = rem >> 5;
    const float* W; bf16* T;
    switch (z) {
      case 0: W = W0; T = T0; break;
      case 1: W = W1; T = T1; break;
      case 2: W = W2; T = T2; break;
      default: W = W3; T = T3; break;
    }
    const int tx = tid & 31, ty = tid >> 5;
    const int bn = bx * 32, bk = by * 32;
#pragma unroll
    for (int i = 0; i < 32; i += 8)
      t[ty + i][tx] = W[(size_t)(bk + ty + i) * 1024 + bn + tx];
    __syncthreads();
#pragma unroll
    for (int i = 0; i < 32; i += 8)
      T[(size_t)(bn + ty + i) * 1024 + bk + tx] = (bf16)t[tx][ty + i];
  } else {
    const int n4 = 1048576;
    int i = (bid - 4096) * 256 + tid;
    const float4* in = (const float4*)x; bf16x4* out = (bf16x4*)xb;
    if (i >= n4) { in = (const float4*)y; out = (bf16x4*)yb; i -= n4; }
    float4 v = in[i];
    bf16x4 o;
    o[0] = (bf16)v.x; o[1] = (bf16)v.y; o[2] = (bf16)v.z; o[3] = (bf16)v.w;
    out[i] = o;
  }
}

// ---------------- merged Q/K/V projection GEMM, 128x128 tile, 8 waves, double-buffered --------
__global__ __launch_bounds__(512, 6) void gemm_qkv(
    const bf16* __restrict__ xb, const bf16* __restrict__ yb,
    const bf16* __restrict__ Wqt, const bf16* __restrict__ Wkt, const bf16* __restrict__ Wvt,
    const float* __restrict__ bq, const float* __restrict__ bk, const float* __restrict__ bv,
    bf16* __restrict__ Qb, bf16* __restrict__ Kb, bf16* __restrict__ Vtb) {
  constexpr int K = 1024;
  constexpr float QSCALE = (float)(1.4426950408889634 / 45.254833995939045);
  __shared__ bf16 As[2][128 * 32];
  __shared__ bf16 Bs[2][128 * 32];
  const int z = blockIdx.z;
  const bf16* A  = (z == 0) ? xb : yb;
  const bf16* Bt = (z == 0) ? Wqt : (z == 1) ? Wkt : Wvt;
  const float* bias = (z == 0) ? bq : (z == 1) ? bk : bv;

  const int tid = threadIdx.x;
  const int wave = tid >> 6, lane = tid & 63;
  const int g = lane >> 4, r15 = lane & 15;
  const int m0 = blockIdx.x * 128, n0 = blockIdx.y * 128;
  const int wr = wave >> 2, wc = wave & 3;

  f32x4 acc[4][2] = {};

  const int rowA = tid >> 2, chA = tid & 3;

  auto stage = [&](int buf, int k0) {
    gload_lds16(A  + (size_t)(m0 + rowA) * K + k0 + chA * 8, (char*)As[buf] + tid * 16);
    gload_lds16(Bt + (size_t)(n0 + rowA) * K + k0 + chA * 8, (char*)Bs[buf] + tid * 16);
  };

  stage(0, 0);
  __syncthreads();
  int cur = 0;
  for (int t = 0; t < K / 32; ++t) {
    if (t + 1 < K / 32) stage(cur ^ 1, (t + 1) * 32);
    bf16x8 af[4], bfr[2];
#pragma unroll
    for (int mi = 0; mi < 4; ++mi)
      af[mi] = *(const bf16x8*)((const char*)As[cur] + ((wr * 64 + mi * 16 + r15) * 64 + g * 16));
#pragma unroll
    for (int nj = 0; nj < 2; ++nj)
      bfr[nj] = *(const bf16x8*)((const char*)Bs[cur] + ((wc * 32 + nj * 16 + r15) * 64 + g * 16));
#pragma unroll
    for (int mi = 0; mi < 4; ++mi)
#pragma unroll
      for (int nj = 0; nj < 2; ++nj)
        acc[mi][nj] = __builtin_amdgcn_mfma_f32_16x16x32_bf16(af[mi], bfr[nj], acc[mi][nj], 0, 0, 0);
    __syncthreads();
    cur ^= 1;
  }

  const float scl = (z == 0) ? QSCALE : 1.0f;
#pragma unroll
  for (int mi = 0; mi < 4; ++mi) {
#pragma unroll
    for (int nj = 0; nj < 2; ++nj) {
      int row = m0 + wr * 64 + mi * 16 + g * 4;
      int col = n0 + wc * 32 + nj * 16 + r15;
      float bv_ = bias[col];
      if (z < 2) {
        bf16* C = (z == 0) ? Qb : Kb;
#pragma unroll
        for (int r = 0; r < 4; ++r)
          C[(size_t)(row + r) * 1024 + col] = (bf16)((acc[mi][nj][r] + bv_) * scl);
      } else {
        int b = row >> 11, n = row & 2047;
        bf16x4 pkv;
#pragma unroll
        for (int r = 0; r < 4; ++r)
          pkv[r] = (bf16)(acc[mi][nj][r] + bv_);
        *(bf16x4*)(Vtb + ((size_t)b * 1024 + col) * 2048 + n) = pkv;
      }
    }
  }
}

// ---------------- out-projection GEMM, 128x64 tile, 8 waves, bias+ReLU, f32 out ----------------
__global__ __launch_bounds__(512, 4) void gemm_out(
    const bf16* __restrict__ A, const bf16* __restrict__ Bt,
    const float* __restrict__ bias, float* __restrict__ C) {
  constexpr int K = 1024;
  __shared__ bf16 As[2][128 * 32];
  __shared__ bf16 Bs[2][64 * 32];
  const int tid = threadIdx.x;
  const int wave = tid >> 6, lane = tid & 63;
  const int g = lane >> 4, r15 = lane & 15;
  const int m0 = blockIdx.x * 128, n0 = blockIdx.y * 64;
  const int wr = wave >> 1, wc = wave & 1;

  f32x4 acc[2][2] = {};

  const int rowA = tid >> 2, chA = tid & 3;

  auto stage = [&](int buf, int k0) {
    gload_lds16(A + (size_t)(m0 + rowA) * K + k0 + chA * 8, (char*)As[buf] + tid * 16);
    if (tid < 256)
      gload_lds16(Bt + (size_t)(n0 + rowA) * K + k0 + chA * 8, (char*)Bs[buf] + tid * 16);
  };

  stage(0, 0);
  __syncthreads();
  int cur = 0;
  for (int t = 0; t < K / 32; ++t) {
    if (t + 1 < K / 32) stage(cur ^ 1, (t + 1) * 32);
    bf16x8 af[2], bfr[2];
#pragma unroll
    for (int mi = 0; mi < 2; ++mi)
      af[mi] = *(const bf16x8*)((const char*)As[cur] + ((wr * 32 + mi * 16 + r15) * 64 + g * 16));
#pragma unroll
    for (int nj = 0; nj < 2; ++nj)
      bfr[nj] = *(const bf16x8*)((const char*)Bs[cur] + ((wc * 32 + nj * 16 + r15) * 64 + g * 16));
#pragma unroll
    for (int mi = 0; mi < 2; ++mi)
#pragma unroll
      for (int nj = 0; nj < 2; ++nj)
        acc[mi][nj] = __builtin_amdgcn_mfma_f32_16x16x32_bf16(af[mi], bfr[nj], acc[mi][nj], 0, 0, 0);
    __syncthreads();
    cur ^= 1;
  }

#pragma unroll
  for (int mi = 0; mi < 2; ++mi)
#pragma unroll
    for (int nj = 0; nj < 2; ++nj) {
      int row = m0 + wr * 32 + mi * 16 + g * 4;
      int col = n0 + wc * 32 + nj * 16 + r15;
      float bv_ = bias[col];
#pragma unroll
      for (int r = 0; r < 4; ++r)
        C[(size_t)(row + r) * 1024 + col] = fmaxf(acc[mi][nj][r] + bv_, 0.0f);
    }
}

// ---------------- flash attention v8-builtin (oracle-validated R11 shadow1) --------------------
// QBLK=32, 2048 blocks XCD-grouped, 2 waves kv-split; K dbuf in LDS (16KB); V direct from
// global (L2-resident per-XCD panels); att[2] pipeline; builtin exp2/permlane (hazard-safe).
// Q prescaled by log2e/sqrt(2048). Q,K: [B][2048][1024] bf16. V^T: [B][1024][2048] bf16.
__global__ __launch_bounds__(128, 4) void attn_kernel(
    const bf16* __restrict__ Q, const bf16* __restrict__ Kin,
    const bf16* __restrict__ Vt, bf16* __restrict__ Oa) {
  __shared__ bf16 Ks[2][64 * 64];
  __shared__ float lsh[2][32];
  const int tid = threadIdx.x;
  const int w = tid >> 6, lane = tid & 63;
  const int q5 = lane & 31, h = lane >> 5;

  // XCD-grouped mapping: 2048 blocks = 8 XCD x (4 bh panels x 64 q-tiles)
  int i = blockIdx.y * 64 + blockIdx.x;
  int xcd = i & 7, slot = i >> 3;
  int bh = xcd * 4 + (slot >> 6), qt = slot & 63;
  int b = bh >> 4, hd = bh & 15;

  const bf16* Qg = Q + ((size_t)b * 2048 + qt * 32) * 1024 + hd * 64;
  const bf16* Kg = Kin + (size_t)b * 2048 * 1024 + hd * 64;
  const bf16* Vg = Vt + ((size_t)b * 1024 + hd * 64) * 2048;

  // Q B-fragments: lane holds Q[q = q5][k = 16ks+8h+j]
  bf16x8 qf[4];
#pragma unroll
  for (int ks = 0; ks < 4; ++ks)
    qf[ks] = *(const bf16x8*)(Qg + (size_t)q5 * 1024 + ks * 16 + h * 8);

  f32x16 o[2] = {};  // [j]: j=0 -> own d-block (db=w), j=1 -> partner (db=1-w)
  float ls = 0.0f;

  auto stage = [&](int buf, int kv0) {
#pragma unroll
    for (int ii = 0; ii < 4; ++ii) {
      int c = tid + ii * 128;
      int row = c >> 3;
      int sl = (c & 7) ^ (row & 7) ^ ((row >> 3) & 1);  // pre-swizzled global source chunk
      gload_lds16(Kg + (size_t)(kv0 + row) * 1024 + sl * 8, (char*)Ks[buf] + c * 16);
    }
  };

  stage(0, 0);
  __syncthreads();
  int cur = 0;

  const int krow = w * 32 + q5;
  const int kswz = (krow & 7) ^ ((krow >> 3) & 1);

  // two-deep pipeline state (static names — no runtime-indexed arrays)
  unsigned uA[8], uB[8];
  bf16x8 vA[4], vB[4];

  // phase: QK(t) + ldV(t)->vout (global) + PV(t-1) from uin/vin + exp/pack(t)->uout
  auto phase = [&](int t, unsigned (&uin)[8], unsigned (&uout)[8],
                   bf16x8 (&vin)[4], bf16x8 (&vout)[4], bool doStage, bool doPV) {
    if (doStage) stage(cur ^ 1, (t + 1) * 64);

    // S^T = K_w * Q^T : 32kv x 32q
    f32x16 s = {};
    __builtin_amdgcn_s_setprio(1);
#pragma unroll
    for (int ks = 0; ks < 4; ++ks) {
      bf16x8 kf = *(const bf16x8*)((const char*)Ks[cur] + krow * 128 + (((2 * ks + h) ^ kswz) << 4));
      s = __builtin_amdgcn_mfma_f32_32x32x16_bf16(kf, qf[ks], s, 0, 0, 0);
    }

    // V(t) fragments -> registers, direct from global (L2-resident)
#pragma unroll
    for (int j = 0; j < 2; ++j) {
      const int db = w ^ j;
#pragma unroll
      for (int kap = 0; kap < 2; ++kap)
        vout[2 * j + kap] = *(const bf16x8*)(Vg + (size_t)(db * 32 + q5) * 2048 +
                                            t * 64 + (4 * w + 2 * kap + h) * 8);
    }

    // PV(t-1): fully register-fed
    if (doPV) {
#pragma unroll
      for (int j = 0; j < 2; ++j)
#pragma unroll
        for (int kap = 0; kap < 2; ++kap) {
          u32x4 uw;
          uw[0] = uin[4 * kap + 0]; uw[1] = uin[4 * kap + 1];
          uw[2] = uin[4 * kap + 2]; uw[3] = uin[4 * kap + 3];
          bf16x8 pa = __builtin_bit_cast(bf16x8, uw);
          o[j] = __builtin_amdgcn_mfma_f32_32x32x16_bf16(pa, vin[2 * j + kap], o[j], 0, 0, 0);
        }
    }
    __builtin_amdgcn_s_setprio(0);

    // P(t) = exp2(S), pack, permlane half-exchange (builtins: hazard-safe)
    float e[16];
#pragma unroll
    for (int jj = 0; jj < 16; ++jj) e[jj] = exp2_b(s[jj]);
    ls += ((((e[0] + e[1]) + (e[2] + e[3])) + ((e[4] + e[5]) + (e[6] + e[7]))) +
           (((e[8] + e[9]) + (e[10] + e[11])) + ((e[12] + e[13]) + (e[14] + e[15]))));
#pragma unroll
    for (int p = 0; p < 8; ++p) uout[p] = cvtpk(e[2 * p], e[2 * p + 1]);
    plswap_b(uout[0], uout[2]); plswap_b(uout[1], uout[3]);
    plswap_b(uout[4], uout[6]); plswap_b(uout[5], uout[7]);

    __syncthreads();
    cur ^= 1;
  };

  phase(0, uB, uA, vB, vA, true, false);
  for (int t = 1; t < 31; t += 2) {
    phase(t, uA, uB, vA, vB, true, true);
    phase(t + 1, uB, uA, vB, vA, true, true);
  }
  phase(31, uA, uB, vA, vB, false, true);
#pragma unroll
  for (int j = 0; j < 2; ++j)
#pragma unroll
    for (int kap = 0; kap < 2; ++kap) {
      u32x4 uw;
      uw[0] = uB[4 * kap + 0]; uw[1] = uB[4 * kap + 1];
      uw[2] = uB[4 * kap + 2]; uw[3] = uB[4 * kap + 3];
      bf16x8 pa = __builtin_bit_cast(bf16x8, uw);
      o[j] = __builtin_amdgcn_mfma_f32_32x32x16_bf16(pa, vB[2 * j + kap], o[j], 0, 0, 0);
    }

  // ls: cross-h reduce; publish per-wave
  ls += __shfl_xor(ls, 32);
  if (h == 0) lsh[w][q5] = ls;

  // cross-wave O combine via Ks overlay (dead after last tile)
  float* osh = (float*)Ks;  // [2 waves][64 lanes][16] f32 = 8 KB
  *(f32x16*)(osh + ((size_t)(w * 64 + lane)) * 16) = o[1];
  __syncthreads();

  const int pw = 1 - w;
  float lt = ls + lsh[pw][q5];
  float iv = __builtin_amdgcn_rcpf(lt);
  f32x16 p = *(const f32x16*)(osh + ((size_t)(pw * 64 + lane)) * 16);
#pragma unroll
  for (int g4 = 0; g4 < 4; ++g4)
#pragma unroll
    for (int r = 0; r < 4; ++r) {
      int qr = g4 * 8 + 4 * h + r;
      float il = __shfl(iv, qr);
      size_t row = (size_t)b * 2048 + qt * 32 + qr;
      Oa[row * 1024 + hd * 64 + w * 32 + q5] = (bf16)((o[0][g4 * 4 + r] + p[g4 * 4 + r]) * il);
    }
}

extern "C" void kernel_launch(void* const* d_in, const int* in_sizes, int n_in,
                              void* d_out, int out_size, void* d_ws, size_t ws_size,
                              hipStream_t stream) {
  (void)in_sizes; (void)n_in; (void)out_size; (void)ws_size;
  const float* x  = (const float*)d_in[0];
  const float* y  = (const float*)d_in[1];
  const float* Wq = (const float*)d_in[2];
  const float* bq = (const float*)d_in[3];
  const float* Wk = (const float*)d_in[4];
  const float* bk = (const float*)d_in[5];
  const float* Wv = (const float*)d_in[6];
  const float* bv = (const float*)d_in[7];
  const float* Wo = (const float*)d_in[8];
  const float* bo = (const float*)d_in[9];

  char* ws = (char*)d_ws;
  bf16* xb  = (bf16*)(ws + 0);
  bf16* yb  = (bf16*)(ws + 8388608);
  bf16* Qb  = (bf16*)(ws + 16777216);
  bf16* Kb  = (bf16*)(ws + 25165824);
  bf16* Vtb = (bf16*)(ws + 33554432);
  bf16* Oab = (bf16*)(ws + 41943040);
  bf16* Wqt = (bf16*)(ws + 50331648);
  bf16* Wkt = (bf16*)(ws + 52428800);
  bf16* Wvt = (bf16*)(ws + 54525952);
  bf16* Wot = (bf16*)(ws + 56623104);

  cvtw_kernel<<<12288, 256, 0, stream>>>(x, y, xb, yb, Wq, Wk, Wv, Wo, Wqt, Wkt, Wvt, Wot);
  gemm_qkv<<<dim3(32, 8, 3), 512, 0, stream>>>(xb, yb, Wqt, Wkt, Wvt, bq, bk, bv, Qb, Kb, Vtb);
  attn_kernel<<<dim3(64, 32), dim3(128), 0, stream>>>(Qb, Kb, Vtb, Oab);
  gemm_out<<<dim3(32, 16), 512, 0, stream>>>(Oab, Wot, bo, (float*)d_out);
}

// Round 13
// 118.428 us; speedup vs baseline: 70.1846x; 1.2543x over previous
//
#include <hip/hip_runtime.h>
#include <hip/hip_bf16.h>

typedef __bf16 bf16;
typedef __attribute__((ext_vector_type(8))) __bf16 bf16x8;
typedef __attribute__((ext_vector_type(4))) __bf16 bf16x4;
typedef __attribute__((ext_vector_type(4))) float f32x4;
typedef __attribute__((ext_vector_type(16))) float f32x16;
typedef __attribute__((ext_vector_type(4))) unsigned int u32x4;
typedef __attribute__((ext_vector_type(2))) unsigned int u32x2;

__device__ __forceinline__ void gload_lds16(const void* g, void* l) {
  __builtin_amdgcn_global_load_lds((const __attribute__((address_space(1))) void*)g,
                                   (__attribute__((address_space(3))) void*)l, 16, 0, 0);
}

// R11 lesson: raw inline-asm v_exp_f32 / v_permlane32_swap lack compiler-managed result-use
// hazard handling -> schedule-dependent corruption (R6/R7/R9, oracle-confirmed R11). Builtins only.
__device__ __forceinline__ float exp2_b(float x) { return __builtin_amdgcn_exp2f(x); }
__device__ __forceinline__ void plswap_b(unsigned& a, unsigned& b) {
  u32x2 r = __builtin_amdgcn_permlane32_swap(a, b, false, false);
  a = r[0]; b = r[1];
}
// cvt_pk: no builtin exists; non-TRANS VALU op, oracle-validated safe in asm.
__device__ __forceinline__ unsigned cvtpk(float lo, float hi) {
  unsigned r;
  asm("v_cvt_pk_bf16_f32 %0, %1, %2" : "=v"(r) : "v"(lo), "v"(hi));
  return r;
}

// ---------------- merged f32->bf16 convert (x,y) + weight transpose-convert ----------------
__global__ __launch_bounds__(256) void cvtw_kernel(
    const float* __restrict__ x, const float* __restrict__ y,
    bf16* __restrict__ xb, bf16* __restrict__ yb,
    const float* __restrict__ W0, const float* __restrict__ W1,
    const float* __restrict__ W2, const float* __restrict__ W3,
    bf16* __restrict__ T0, bf16* __restrict__ T1,
    bf16* __restrict__ T2, bf16* __restrict__ T3) {
  __shared__ float t[32][33];
  const int bid = blockIdx.x, tid = threadIdx.x;
  if (bid < 4096) {
    const int z = bid >> 10, rem = bid & 1023;
    const int bx = rem & 31, by = rem >> 5;
    const float* W; bf16* T;
    switch (z) {
      case 0: W = W0; T = T0; break;
      case 1: W = W1; T = T1; break;
      case 2: W = W2; T = T2; break;
      default: W = W3; T = T3; break;
    }
    const int tx = tid & 31, ty = tid >> 5;
    const int bn = bx * 32, bk = by * 32;
#pragma unroll
    for (int i = 0; i < 32; i += 8)
      t[ty + i][tx] = W[(size_t)(bk + ty + i) * 1024 + bn + tx];
    __syncthreads();
#pragma unroll
    for (int i = 0; i < 32; i += 8)
      T[(size_t)(bn + ty + i) * 1024 + bk + tx] = (bf16)t[tx][ty + i];
  } else {
    const int n4 = 1048576;
    int i = (bid - 4096) * 256 + tid;
    const float4* in = (const float4*)x; bf16x4* out = (bf16x4*)xb;
    if (i >= n4) { in = (const float4*)y; out = (bf16x4*)yb; i -= n4; }
    float4 v = in[i];
    bf16x4 o;
    o[0] = (bf16)v.x; o[1] = (bf16)v.y; o[2] = (bf16)v.z; o[3] = (bf16)v.w;
    out[i] = o;
  }
}

// ---------------- merged Q/K/V projection GEMM, 128x128 tile, 8 waves, double-buffered --------
__global__ __launch_bounds__(512, 6) void gemm_qkv(
    const bf16* __restrict__ xb, const bf16* __restrict__ yb,
    const bf16* __restrict__ Wqt, const bf16* __restrict__ Wkt, const bf16* __restrict__ Wvt,
    const float* __restrict__ bq, const float* __restrict__ bk, const float* __restrict__ bv,
    bf16* __restrict__ Qb, bf16* __restrict__ Kb, bf16* __restrict__ Vtb) {
  constexpr int K = 1024;
  constexpr float QSCALE = (float)(1.4426950408889634 / 45.254833995939045);
  __shared__ bf16 As[2][128 * 32];
  __shared__ bf16 Bs[2][128 * 32];
  const int z = blockIdx.z;
  const bf16* A  = (z == 0) ? xb : yb;
  const bf16* Bt = (z == 0) ? Wqt : (z == 1) ? Wkt : Wvt;
  const float* bias = (z == 0) ? bq : (z == 1) ? bk : bv;

  const int tid = threadIdx.x;
  const int wave = tid >> 6, lane = tid & 63;
  const int g = lane >> 4, r15 = lane & 15;
  const int m0 = blockIdx.x * 128, n0 = blockIdx.y * 128;
  const int wr = wave >> 2, wc = wave & 3;

  f32x4 acc[4][2] = {};

  const int rowA = tid >> 2, chA = tid & 3;

  auto stage = [&](int buf, int k0) {
    gload_lds16(A  + (size_t)(m0 + rowA) * K + k0 + chA * 8, (char*)As[buf] + tid * 16);
    gload_lds16(Bt + (size_t)(n0 + rowA) * K + k0 + chA * 8, (char*)Bs[buf] + tid * 16);
  };

  stage(0, 0);
  __syncthreads();
  int cur = 0;
  for (int t = 0; t < K / 32; ++t) {
    if (t + 1 < K / 32) stage(cur ^ 1, (t + 1) * 32);
    bf16x8 af[4], bfr[2];
#pragma unroll
    for (int mi = 0; mi < 4; ++mi)
      af[mi] = *(const bf16x8*)((const char*)As[cur] + ((wr * 64 + mi * 16 + r15) * 64 + g * 16));
#pragma unroll
    for (int nj = 0; nj < 2; ++nj)
      bfr[nj] = *(const bf16x8*)((const char*)Bs[cur] + ((wc * 32 + nj * 16 + r15) * 64 + g * 16));
#pragma unroll
    for (int mi = 0; mi < 4; ++mi)
#pragma unroll
      for (int nj = 0; nj < 2; ++nj)
        acc[mi][nj] = __builtin_amdgcn_mfma_f32_16x16x32_bf16(af[mi], bfr[nj], acc[mi][nj], 0, 0, 0);
    __syncthreads();
    cur ^= 1;
  }

  const float scl = (z == 0) ? QSCALE : 1.0f;
#pragma unroll
  for (int mi = 0; mi < 4; ++mi) {
#pragma unroll
    for (int nj = 0; nj < 2; ++nj) {
      int row = m0 + wr * 64 + mi * 16 + g * 4;
      int col = n0 + wc * 32 + nj * 16 + r15;
      float bv_ = bias[col];
      if (z < 2) {
        bf16* C = (z == 0) ? Qb : Kb;
#pragma unroll
        for (int r = 0; r < 4; ++r)
          C[(size_t)(row + r) * 1024 + col] = (bf16)((acc[mi][nj][r] + bv_) * scl);
      } else {
        int b = row >> 11, n = row & 2047;
        bf16x4 pkv;
#pragma unroll
        for (int r = 0; r < 4; ++r)
          pkv[r] = (bf16)(acc[mi][nj][r] + bv_);
        *(bf16x4*)(Vtb + ((size_t)b * 1024 + col) * 2048 + n) = pkv;
      }
    }
  }
}

// ---------------- out-projection GEMM, 128x64 tile, 8 waves, bias+ReLU, f32 out ----------------
__global__ __launch_bounds__(512, 4) void gemm_out(
    const bf16* __restrict__ A, const bf16* __restrict__ Bt,
    const float* __restrict__ bias, float* __restrict__ C) {
  constexpr int K = 1024;
  __shared__ bf16 As[2][128 * 32];
  __shared__ bf16 Bs[2][64 * 32];
  const int tid = threadIdx.x;
  const int wave = tid >> 6, lane = tid & 63;
  const int g = lane >> 4, r15 = lane & 15;
  const int m0 = blockIdx.x * 128, n0 = blockIdx.y * 64;
  const int wr = wave >> 1, wc = wave & 1;

  f32x4 acc[2][2] = {};

  const int rowA = tid >> 2, chA = tid & 3;

  auto stage = [&](int buf, int k0) {
    gload_lds16(A + (size_t)(m0 + rowA) * K + k0 + chA * 8, (char*)As[buf] + tid * 16);
    if (tid < 256)
      gload_lds16(Bt + (size_t)(n0 + rowA) * K + k0 + chA * 8, (char*)Bs[buf] + tid * 16);
  };

  stage(0, 0);
  __syncthreads();
  int cur = 0;
  for (int t = 0; t < K / 32; ++t) {
    if (t + 1 < K / 32) stage(cur ^ 1, (t + 1) * 32);
    bf16x8 af[2], bfr[2];
#pragma unroll
    for (int mi = 0; mi < 2; ++mi)
      af[mi] = *(const bf16x8*)((const char*)As[cur] + ((wr * 32 + mi * 16 + r15) * 64 + g * 16));
#pragma unroll
    for (int nj = 0; nj < 2; ++nj)
      bfr[nj] = *(const bf16x8*)((const char*)Bs[cur] + ((wc * 32 + nj * 16 + r15) * 64 + g * 16));
#pragma unroll
    for (int mi = 0; mi < 2; ++mi)
#pragma unroll
      for (int nj = 0; nj < 2; ++nj)
        acc[mi][nj] = __builtin_amdgcn_mfma_f32_16x16x32_bf16(af[mi], bfr[nj], acc[mi][nj], 0, 0, 0);
    __syncthreads();
    cur ^= 1;
  }

#pragma unroll
  for (int mi = 0; mi < 2; ++mi)
#pragma unroll
    for (int nj = 0; nj < 2; ++nj) {
      int row = m0 + wr * 32 + mi * 16 + g * 4;
      int col = n0 + wc * 32 + nj * 16 + r15;
      float bv_ = bias[col];
#pragma unroll
      for (int r = 0; r < 4; ++r)
        C[(size_t)(row + r) * 1024 + col] = fmaxf(acc[mi][nj][r] + bv_, 0.0f);
    }
}

// ---------------- flash attention v6-builtin: 4 waves (kv-half x q-half), att[2] pipeline ------
// R6 structure (algebra quadruple-verified) with the R11-proven builtin fix for the asm
// TRANS/permlane hazard that caused R6/R7's failures. QBLK=64/block, 1024 blocks x 4 waves
// = 16 waves/CU; per-SIMD MFMA pressure equals v5 but 2x waves hide the serial chain.
// Q prescaled by log2e/sqrt(2048). Q,K: [B][2048][1024] bf16. V^T: [B][1024][2048] bf16.
__global__ __launch_bounds__(256, 4) void attn_kernel(
    const bf16* __restrict__ Q, const bf16* __restrict__ Kin,
    const bf16* __restrict__ Vt, bf16* __restrict__ Oa) {
  __shared__ bf16 Ks[2][64 * 64];
  __shared__ bf16 Vs[2][64 * 64];
  const int tid = threadIdx.x;
  const int w = tid >> 6, lane = tid & 63;
  const int q5 = lane & 31, h = lane >> 5;
  const int kh = w & 1, qh = w >> 1;

  // XCD-grouped mapping: each XCD owns 4 bh panels x 32 q-tiles
  int i = blockIdx.y * 32 + blockIdx.x;
  int xcd = i & 7, slot = i >> 3;
  int bh = xcd * 4 + (slot >> 5), qt = slot & 31;
  int b = bh >> 4, hd = bh & 15;

  const bf16* Qg = Q + ((size_t)b * 2048 + qt * 64 + qh * 32) * 1024 + hd * 64;
  const bf16* Kg = Kin + (size_t)b * 2048 * 1024 + hd * 64;
  const bf16* Vg = Vt + ((size_t)b * 1024 + hd * 64) * 2048;

  // Q B-fragments: lane holds Q[q = qh*32+q5][k = 16ks+8h+j]
  bf16x8 qf[4];
#pragma unroll
  for (int ks = 0; ks < 4; ++ks)
    qf[ks] = *(const bf16x8*)(Qg + (size_t)q5 * 1024 + ks * 16 + h * 8);

  f32x16 o[2] = {};  // [j]: j=0 -> own d-block (db=kh), j=1 -> partner (db=1-kh)
  float ls = 0.0f;

  auto stage = [&](int buf, int kv0) {
#pragma unroll
    for (int ii = 0; ii < 2; ++ii) {
      int c = tid + ii * 256;
      int row = c >> 3;
      int sl = (c & 7) ^ (row & 7) ^ ((row >> 3) & 1);  // pre-swizzled global source chunk
      gload_lds16(Kg + (size_t)(kv0 + row) * 1024 + sl * 8, (char*)Ks[buf] + c * 16);
      gload_lds16(Vg + (size_t)row * 2048 + kv0 + sl * 8, (char*)Vs[buf] + c * 16);
    }
  };

  stage(0, 0);
  __syncthreads();
  int cur = 0;

  const int krow = kh * 32 + q5;
  const int kswz = (krow & 7) ^ ((krow >> 3) & 1);

  // two-deep pipeline state (static names — no runtime-indexed arrays)
  unsigned uA[8], uB[8];
  bf16x8 vA[4], vB[4];

  // one pipeline phase: QK(t) + ldV(t)->vout + PV(t-1) from uin/vin + exp/pack(t)->uout
  auto phase = [&](int t, unsigned (&uin)[8], unsigned (&uout)[8],
                   bf16x8 (&vin)[4], bf16x8 (&vout)[4], bool doStage, bool doPV) {
    if (doStage) stage(cur ^ 1, (t + 1) * 64);

    // S^T = K_kh * Q_qh^T : 32kv x 32q
    f32x16 s = {};
    __builtin_amdgcn_s_setprio(1);
#pragma unroll
    for (int ks = 0; ks < 4; ++ks) {
      bf16x8 kf = *(const bf16x8*)((const char*)Ks[cur] + krow * 128 + (((2 * ks + h) ^ kswz) << 4));
      s = __builtin_amdgcn_mfma_f32_32x32x16_bf16(kf, qf[ks], s, 0, 0, 0);
    }

    // V(t) fragments -> registers
#pragma unroll
    for (int j = 0; j < 2; ++j) {
      const int db = kh ^ j;
      const int vrow0 = db * 32 + q5;
      const int vswz = (vrow0 & 7) ^ ((vrow0 >> 3) & 1);
#pragma unroll
      for (int kap = 0; kap < 2; ++kap)
        vout[2 * j + kap] = *(const bf16x8*)((const char*)Vs[cur] + vrow0 * 128 +
                                             (((4 * kh + 2 * kap + h) ^ vswz) << 4));
    }

    // PV(t-1): fully register-fed, fills MFMA pipe while s(t) drains
    if (doPV) {
#pragma unroll
      for (int j = 0; j < 2; ++j)
#pragma unroll
        for (int kap = 0; kap < 2; ++kap) {
          u32x4 uw;
          uw[0] = uin[4 * kap + 0]; uw[1] = uin[4 * kap + 1];
          uw[2] = uin[4 * kap + 2]; uw[3] = uin[4 * kap + 3];
          bf16x8 pa = __builtin_bit_cast(bf16x8, uw);
          o[j] = __builtin_amdgcn_mfma_f32_32x32x16_bf16(pa, vin[2 * j + kap], o[j], 0, 0, 0);
        }
    }
    __builtin_amdgcn_s_setprio(0);

    // P(t) = exp2(S), pack, permlane half-exchange (builtins: hazard-safe)
    float e[16];
#pragma unroll
    for (int jj = 0; jj < 16; ++jj) e[jj] = exp2_b(s[jj]);
    ls += ((((e[0] + e[1]) + (e[2] + e[3])) + ((e[4] + e[5]) + (e[6] + e[7]))) +
           (((e[8] + e[9]) + (e[10] + e[11])) + ((e[12] + e[13]) + (e[14] + e[15]))));
#pragma unroll
    for (int p = 0; p < 8; ++p) uout[p] = cvtpk(e[2 * p], e[2 * p + 1]);
    plswap_b(uout[0], uout[2]); plswap_b(uout[1], uout[3]);
    plswap_b(uout[4], uout[6]); plswap_b(uout[5], uout[7]);

    __syncthreads();
    cur ^= 1;
  };

  // prologue: tile 0 (no PV)
  phase(0, uB, uA, vB, vA, true, false);
  // steady state: tiles 1..30 in pairs
  for (int t = 1; t < 31; t += 2) {
    phase(t, uA, uB, vA, vB, true, true);
    phase(t + 1, uB, uA, vB, vA, true, true);
  }
  // tail: tile 31 (no stage), then final PV(31)
  phase(31, uA, uB, vA, vB, false, true);
#pragma unroll
  for (int j = 0; j < 2; ++j)
#pragma unroll
    for (int kap = 0; kap < 2; ++kap) {
      u32x4 uw;
      uw[0] = uB[4 * kap + 0]; uw[1] = uB[4 * kap + 1];
      uw[2] = uB[4 * kap + 2]; uw[3] = uB[4 * kap + 3];
      bf16x8 pa = __builtin_bit_cast(bf16x8, uw);
      o[j] = __builtin_amdgcn_mfma_f32_32x32x16_bf16(pa, vB[2 * j + kap], o[j], 0, 0, 0);
    }

  // ls: cross-h reduce -> every lane holds this wave's 32-kv half-sum for q=q5
  ls += __shfl_xor(ls, 32);

  // cross-wave combine via LDS overlay (Ks/Vs dead after last tile; same pattern passes in v5)
  float* osh = (float*)Ks;  // [4 waves][64 lanes][16] f32 = 16 KB
  float* lsf = (float*)Vs;  // [4 waves][32] f32
  *(f32x16*)(osh + ((size_t)(w * 64 + lane)) * 16) = o[1];
  if (h == 0) lsf[w * 32 + q5] = ls;
  __syncthreads();

  const int pw = w ^ 1;  // partner: same q-half, other kv-half
  float lt = ls + lsf[pw * 32 + q5];
  float iv = __builtin_amdgcn_rcpf(lt);
  f32x16 p = *(const f32x16*)(osh + ((size_t)(pw * 64 + lane)) * 16);
#pragma unroll
  for (int g4 = 0; g4 < 4; ++g4)
#pragma unroll
    for (int r = 0; r < 4; ++r) {
      int qr = g4 * 8 + 4 * h + r;
      float il = __shfl(iv, qr);
      size_t row = (size_t)b * 2048 + qt * 64 + qh * 32 + qr;
      Oa[row * 1024 + hd * 64 + kh * 32 + q5] = (bf16)((o[0][g4 * 4 + r] + p[g4 * 4 + r]) * il);
    }
}

extern "C" void kernel_launch(void* const* d_in, const int* in_sizes, int n_in,
                              void* d_out, int out_size, void* d_ws, size_t ws_size,
                              hipStream_t stream) {
  (void)in_sizes; (void)n_in; (void)out_size; (void)ws_size;
  const float* x  = (const float*)d_in[0];
  const float* y  = (const float*)d_in[1];
  const float* Wq = (const float*)d_in[2];
  const float* bq = (const float*)d_in[3];
  const float* Wk = (const float*)d_in[4];
  const float* bk = (const float*)d_in[5];
  const float* Wv = (const float*)d_in[6];
  const float* bv = (const float*)d_in[7];
  const float* Wo = (const float*)d_in[8];
  const float* bo = (const float*)d_in[9];

  char* ws = (char*)d_ws;
  bf16* xb  = (bf16*)(ws + 0);
  bf16* yb  = (bf16*)(ws + 8388608);
  bf16* Qb  = (bf16*)(ws + 16777216);
  bf16* Kb  = (bf16*)(ws + 25165824);
  bf16* Vtb = (bf16*)(ws + 33554432);
  bf16* Oab = (bf16*)(ws + 41943040);
  bf16* Wqt = (bf16*)(ws + 50331648);
  bf16* Wkt = (bf16*)(ws + 52428800);
  bf16* Wvt = (bf16*)(ws + 54525952);
  bf16* Wot = (bf16*)(ws + 56623104);

  cvtw_kernel<<<12288, 256, 0, stream>>>(x, y, xb, yb, Wq, Wk, Wv, Wo, Wqt, Wkt, Wvt, Wot);
  gemm_qkv<<<dim3(32, 8, 3), 512, 0, stream>>>(xb, yb, Wqt, Wkt, Wvt, bq, bk, bv, Qb, Kb, Vtb);
  attn_kernel<<<dim3(32, 32), dim3(256), 0, stream>>>(Qb, Kb, Vtb, Oab);
  gemm_out<<<dim3(32, 16), 512, 0, stream>>>(Oab, Wot, bo, (float*)d_out);
}